// Round 2
// baseline (261.650 us; speedup 1.0000x reference)
//
#include <hip/hip_runtime.h>
#include <math.h>

#define NATOMS 4096
#define R_CUT 5.0f
#define JPT 4                 // j's per thread (strided by BLOCK)
#define BLOCK 256
#define JPB (BLOCK * JPT)     // 1024 j's per block tile
#define IPB 8                 // rows per block: j-tile register reuse factor

// 12-byte vector store type; natural v3 alignment is 16, force 4 so the
// (i*4096+j)*12-byte addresses are legal. gfx9 global path handles any
// 4B-aligned dwordx3.
typedef float f3 __attribute__((ext_vector_type(3), aligned(4)));

__global__ __launch_bounds__(BLOCK) void radius_graph_kernel(
    const float* __restrict__ pos,    // [N,3]
    const float* __restrict__ cell,   // [B,3,3]
    const int*   __restrict__ batch,  // [N]
    float* __restrict__ disp_out,     // [N,N,3]
    float* __restrict__ mask_out)     // [N,N] as 0/1 float
{
    const int bid = blockIdx.x;
    const int rg  = bid >> 2;        // row-group: 8 consecutive rows
    const int jc  = bid & 3;         // j-chunk: 4 chunks of 1024 j's
    const int tid = (int)threadIdx.x;

    // ---- STRIDED j-ownership: thread tid owns j = jc*1024 + k*256 + tid.
    // Each lane's 12 B disp chunk is contiguous with its neighbor lane's ->
    // direct global_store_dwordx3 is coalesced (768 B/instr, full 64B lines).
    // No LDS staging, no barriers anywhere in the kernel.
    float pjx[JPT], pjy[JPT], pjz[JPT];
    int   bj[JPT];
    #pragma unroll
    for (int k = 0; k < JPT; ++k) {
        const int j = jc * JPB + k * BLOCK + tid;
        pjx[k] = pos[j * 3 + 0];
        pjy[k] = pos[j * 3 + 1];
        pjz[k] = pos[j * 3 + 2];
        bj[k]  = batch[j];
    }

    const int i0 = rg * IPB;

    #pragma unroll 1
    for (int r = 0; r < IPB; ++r) {
        const int i = i0 + r;

        // Wave-uniform row data: scalar loads; every thread redundantly
        // computes the 3x3 inverse (cheap, ~40 VALU ops/row).
        const int bi = batch[i];
        const float pix = pos[i * 3 + 0];
        const float piy = pos[i * 3 + 1];
        const float piz = pos[i * 3 + 2];

        const float* C = cell + (size_t)bi * 9;
        const float C00 = C[0], C01 = C[1], C02 = C[2];
        const float C10 = C[3], C11 = C[4], C12 = C[5];
        const float C20 = C[6], C21 = C[7], C22 = C[8];
        // A = inv(C^T) = cofactor(C) / det(C)
        const float cof00 =  (C11 * C22 - C12 * C21);
        const float cof01 = -(C10 * C22 - C12 * C20);
        const float cof02 =  (C10 * C21 - C11 * C20);
        const float cof10 = -(C01 * C22 - C02 * C21);
        const float cof11 =  (C00 * C22 - C02 * C20);
        const float cof12 = -(C00 * C21 - C01 * C20);
        const float cof20 =  (C01 * C12 - C02 * C11);
        const float cof21 = -(C00 * C12 - C02 * C10);
        const float cof22 =  (C00 * C11 - C01 * C10);
        const float det = C00 * cof00 + C01 * cof01 + C02 * cof02;
        const float id  = 1.0f / det;
        const float A00 = cof00 * id, A01 = cof01 * id, A02 = cof02 * id;
        const float A10 = cof10 * id, A11 = cof11 * id, A12 = cof12 * id;
        const float A20 = cof20 * id, A21 = cof21 * id, A22 = cof22 * id;

        const size_t rowm = (size_t)i * NATOMS;          // mask row base (floats)
        const size_t rowd = rowm * 3;                    // disp row base (floats)

        #pragma unroll
        for (int k = 0; k < JPT; ++k) {
            const int j = jc * JPB + k * BLOCK + tid;
            // raw displacement, exact-order f32 (matches numpy, no fma contraction)
            const float d0 = __fsub_rn(pix, pjx[k]);
            const float d1 = __fsub_rn(piy, pjy[k]);
            const float d2 = __fsub_rn(piz, pjz[k]);

            // scaled = inv(cell^T) @ d
            const float s0 = __fadd_rn(__fadd_rn(__fmul_rn(A00, d0), __fmul_rn(A01, d1)), __fmul_rn(A02, d2));
            const float s1 = __fadd_rn(__fadd_rn(__fmul_rn(A10, d0), __fmul_rn(A11, d1)), __fmul_rn(A12, d2));
            const float s2 = __fadd_rn(__fadd_rn(__fmul_rn(A20, d0), __fmul_rn(A21, d1)), __fmul_rn(A22, d2));

            const float r0 = rintf(s0);   // round-half-even == jnp.round
            const float r1 = rintf(s1);
            const float r2 = rintf(s2);

            // wrapped = d - cell @ r, exact numpy order, no contraction
            const float w0 = __fsub_rn(d0, __fadd_rn(__fadd_rn(__fmul_rn(C00, r0), __fmul_rn(C01, r1)), __fmul_rn(C02, r2)));
            const float w1 = __fsub_rn(d1, __fadd_rn(__fadd_rn(__fmul_rn(C10, r0), __fmul_rn(C11, r1)), __fmul_rn(C12, r2)));
            const float w2 = __fsub_rn(d2, __fadd_rn(__fadd_rn(__fmul_rn(C20, r0), __fmul_rn(C21, r1)), __fmul_rn(C22, r2)));

            const float n2 = __fadd_rn(__fadd_rn(__fmul_rn(w0, w0), __fmul_rn(w1, w1)), __fmul_rn(w2, w2));
            const bool m = (bi == bj[k]) && (i != j) && (sqrtf(n2) < R_CUT);

            // Direct stores: disp dwordx3 is lane-contiguous (12 B/lane),
            // mask dword is lane-contiguous (4 B/lane). Fire-and-forget;
            // no barrier ever waits on these.
            f3 v;
            v.x = m ? w0 : 0.0f;
            v.y = m ? w1 : 0.0f;
            v.z = m ? w2 : 0.0f;
            *(f3*)(disp_out + rowd + (size_t)j * 3) = v;
            mask_out[rowm + (size_t)j] = m ? 1.0f : 0.0f;
        }
    }
}

extern "C" void kernel_launch(void* const* d_in, const int* in_sizes, int n_in,
                              void* d_out, int out_size, void* d_ws, size_t ws_size,
                              hipStream_t stream) {
    const float* pos   = (const float*)d_in[0];
    const float* cell  = (const float*)d_in[1];
    const int*   batch = (const int*)d_in[2];

    float* disp_out = (float*)d_out;
    float* mask_out = (float*)d_out + (size_t)NATOMS * NATOMS * 3;

    const int blocks = (NATOMS / IPB) * (NATOMS / JPB);  // 512 * 4 = 2048
    radius_graph_kernel<<<blocks, BLOCK, 0, stream>>>(pos, cell, batch, disp_out, mask_out);
}